// Round 1
// baseline (751.308 us; speedup 1.0000x reference)
//
#include <hip/hip_runtime.h>
#include <hip/hip_bf16.h>
#include <stdint.h>

// ---------- types ----------
typedef __bf16  bf16x8 __attribute__((ext_vector_type(8)));
typedef float   f32x4  __attribute__((ext_vector_type(4)));

// Problem constants
#define BSZ   8
#define TT    16
#define PP    256
#define DD    1024
#define SS    1024
#define MROWS (BSZ * TT * PP)        // 32768
#define NPOS  (TT * PP * DD)         // 4194304 = 2^22

// ---------- async global->LDS (16B per lane, wave-uniform LDS base) ----------
__device__ __forceinline__ void gload16(const void* g, void* l) {
    __builtin_amdgcn_global_load_lds(
        (const __attribute__((address_space(1))) void*)g,
        (__attribute__((address_space(3))) void*)l,
        16, 0, 0);
}

// ---------- elementwise: XP = bf16(x + pos) ----------
__global__ __launch_bounds__(256) void k_xp(const float* __restrict__ x,
                                            const float* __restrict__ pos,
                                            __bf16* __restrict__ xp) {
    long i = ((long)blockIdx.x * blockDim.x + threadIdx.x) * 8;
    float4 a0 = *(const float4*)(x + i);
    float4 a1 = *(const float4*)(x + i + 4);
    long pi = i & (NPOS - 1);
    float4 p0 = *(const float4*)(pos + pi);
    float4 p1 = *(const float4*)(pos + pi + 4);
    bf16x8 o;
    o[0] = (__bf16)(a0.x + p0.x); o[1] = (__bf16)(a0.y + p0.y);
    o[2] = (__bf16)(a0.z + p0.z); o[3] = (__bf16)(a0.w + p0.w);
    o[4] = (__bf16)(a1.x + p1.x); o[5] = (__bf16)(a1.y + p1.y);
    o[6] = (__bf16)(a1.z + p1.z); o[7] = (__bf16)(a1.w + p1.w);
    *(bf16x8*)(xp + i) = o;
}

// ---------- cast fp32 -> bf16 ----------
__global__ __launch_bounds__(256) void k_cast(const float* __restrict__ in,
                                              __bf16* __restrict__ out, int n) {
    int i = (blockIdx.x * blockDim.x + threadIdx.x) * 8;
    if (i >= n) return;
    float4 a = *(const float4*)(in + i);
    float4 b = *(const float4*)(in + i + 4);
    bf16x8 o;
    o[0] = (__bf16)a.x; o[1] = (__bf16)a.y; o[2] = (__bf16)a.z; o[3] = (__bf16)a.w;
    o[4] = (__bf16)b.x; o[5] = (__bf16)b.y; o[6] = (__bf16)b.z; o[7] = (__bf16)b.w;
    *(bf16x8*)(out + i) = o;
}

// ---------- transpose 1024x1024: out[c][r] = in[r][c] ----------
__global__ void k_transpose_bf(const float* __restrict__ in, __bf16* __restrict__ out) {
    __shared__ float tile[32][33];
    int x = blockIdx.x * 32 + threadIdx.x;
    int y = blockIdx.y * 32 + threadIdx.y;
    tile[threadIdx.y][threadIdx.x] = in[(long)y * 1024 + x];
    __syncthreads();
    int ox = blockIdx.y * 32 + threadIdx.x;
    int oy = blockIdx.x * 32 + threadIdx.y;
    out[(long)oy * 1024 + ox] = (__bf16)tile[threadIdx.x][threadIdx.y];
}

__global__ void k_transpose_f32(const float* __restrict__ in, float* __restrict__ out) {
    __shared__ float tile[32][33];
    int x = blockIdx.x * 32 + threadIdx.x;
    int y = blockIdx.y * 32 + threadIdx.y;
    tile[threadIdx.y][threadIdx.x] = in[(long)y * 1024 + x];
    __syncthreads();
    int ox = blockIdx.y * 32 + threadIdx.x;
    int oy = blockIdx.x * 32 + threadIdx.y;
    out[(long)oy * 1024 + ox] = tile[threadIdx.x][threadIdx.y];
}

// ---------- NT GEMM: C[m,n] = sum_k A[m,k]*B[n,k], M=32768 N=1024 K=1024 ----------
// 128x128 tile, BK=64, 256 threads (4 waves, 2x2), mfma_f32_16x16x32_bf16.
// EPI: 0 = bf16 out + bias[n]; 1 = bf16 out; 2 = f32 out + VO[(m>>8)][n]
template <int EPI>
__global__ __launch_bounds__(256) void gemm_nt(const __bf16* __restrict__ A,
                                               const __bf16* __restrict__ B,
                                               void* __restrict__ Cout,
                                               const float* __restrict__ bias,
                                               const float* __restrict__ VO) {
    constexpr int K = 1024;
    const int tid  = threadIdx.x;
    const int lane = tid & 63;
    const int w    = tid >> 6;          // wave 0..3
    const int wr   = w >> 1, wc = w & 1;
    const long bm  = (long)blockIdx.x * 128;
    const long bn  = (long)blockIdx.y * 128;

    __shared__ __bf16 As[128 * 64];
    __shared__ __bf16 Bs[128 * 64];

    f32x4 acc[4][4];
#pragma unroll
    for (int i = 0; i < 4; ++i)
#pragma unroll
        for (int j = 0; j < 4; ++j) acc[i][j] = (f32x4){0.f, 0.f, 0.f, 0.f};

    // staging source coords for this thread (LDS linear layout [row][64])
    const int sr = (w << 3) + (lane >> 3);    // + j*32
    const int sc = (lane & 7) << 3;
    const __bf16* Ap = A + (bm + sr) * K + sc;
    const __bf16* Bp = B + (bn + sr) * K + sc;

    for (int kt = 0; kt < K; kt += 64) {
        if (kt) __syncthreads();
#pragma unroll
        for (int j = 0; j < 4; ++j) {
            // wave-uniform LDS dest: (j*4 + w)*1024 bytes -> elem (j*2048 + w*512)
            gload16(Ap + (long)j * 32 * K + kt, &As[j * 2048 + w * 512]);
            gload16(Bp + (long)j * 32 * K + kt, &Bs[j * 2048 + w * 512]);
        }
        __syncthreads();

#pragma unroll
        for (int kk = 0; kk < 2; ++kk) {
            const int ko = kk * 32 + ((lane >> 4) << 3);
            bf16x8 af[4], bfr[4];
#pragma unroll
            for (int i = 0; i < 4; ++i) {
                int ar = wr * 64 + i * 16 + (lane & 15);
                af[i]  = *(const bf16x8*)&As[ar * 64 + ko];
                int br = wc * 64 + i * 16 + (lane & 15);
                bfr[i] = *(const bf16x8*)&Bs[br * 64 + ko];
            }
#pragma unroll
            for (int mi = 0; mi < 4; ++mi)
#pragma unroll
                for (int ni = 0; ni < 4; ++ni)
                    acc[mi][ni] = __builtin_amdgcn_mfma_f32_16x16x32_bf16(
                        af[mi], bfr[ni], acc[mi][ni], 0, 0, 0);
        }
    }

    // epilogue: C/D layout col=lane&15, row=(lane>>4)*4+j  [m89-verified]
    const int r0 = (lane >> 4) << 2;
    const int c0 = lane & 15;
#pragma unroll
    for (int mi = 0; mi < 4; ++mi) {
#pragma unroll
        for (int ni = 0; ni < 4; ++ni) {
#pragma unroll
            for (int j = 0; j < 4; ++j) {
                long gm = bm + wr * 64 + mi * 16 + r0 + j;
                long gn = bn + wc * 64 + ni * 16 + c0;
                float val = acc[mi][ni][j];
                if constexpr (EPI == 0) {
                    val += bias[gn];
                    ((__bf16*)Cout)[gm * 1024 + gn] = (__bf16)val;
                } else if constexpr (EPI == 1) {
                    ((__bf16*)Cout)[gm * 1024 + gn] = (__bf16)val;
                } else {
                    ((float*)Cout)[gm * 1024 + gn] = val + VO[(gm >> 8) * 1024 + gn];
                }
            }
        }
    }
}

// ---------- column mean over p: Mbuf[bt][s] = (1/256) sum_p PB[bt*256+p][s] ----------
__global__ __launch_bounds__(128) void k_mean(const __bf16* __restrict__ PB,
                                              float* __restrict__ Mbuf) {
    int bt  = blockIdx.x;          // 0..127
    int tid = threadIdx.x;         // 0..127, covers 8 s each
    const __bf16* p = PB + (long)bt * 256 * 1024 + tid * 8;
    float acc[8];
#pragma unroll
    for (int i = 0; i < 8; ++i) acc[i] = 0.f;
    for (int q = 0; q < 256; ++q) {
        bf16x8 v = *(const bf16x8*)(p + (long)q * 1024);
#pragma unroll
        for (int i = 0; i < 8; ++i) acc[i] += (float)v[i];
    }
#pragma unroll
    for (int i = 0; i < 8; ++i)
        Mbuf[(long)bt * 1024 + tid * 8 + i] = acc[i] * (1.0f / 256.0f);
}

// ---------- state init: state[b][s] = initial_state[s] ----------
__global__ __launch_bounds__(256) void k_init_state(const float* __restrict__ init,
                                                    float* __restrict__ state) {
    int idx = blockIdx.x * 256 + threadIdx.x;   // 0..8191
    state[idx] = init[idx & 1023];
}

// ---------- scan step t: v[b][t][s'] = sum_s state[b][s]*AT[s'][s];
//            state_next[b][s'] = v + Mbuf[b*16+t][s'] ----------
__global__ __launch_bounds__(256) void k_step(const float* __restrict__ AT,
                                              const float* __restrict__ Mbuf,
                                              float* __restrict__ v,
                                              float* __restrict__ state,  // [2][8192]
                                              int t) {
    int gw   = blockIdx.x * 4 + (threadIdx.x >> 6);  // 0..8191
    int b    = gw >> 10;
    int sp   = gw & 1023;
    int lane = threadIdx.x & 63;
    const float* at = AT + (long)sp * 1024 + lane * 16;
    const float* st = state + (t & 1) * 8192 + b * 1024 + lane * 16;
    float acc = 0.f;
#pragma unroll
    for (int i = 0; i < 4; ++i) {
        float4 a = *(const float4*)(at + i * 4);
        float4 s = *(const float4*)(st + i * 4);
        acc += a.x * s.x + a.y * s.y + a.z * s.z + a.w * s.w;
    }
#pragma unroll
    for (int off = 32; off; off >>= 1) acc += __shfl_xor(acc, off);
    if (lane == 0) {
        float vt = acc;
        long bt = (long)b * 16 + t;
        v[bt * 1024 + sp] = vt;
        state[((t + 1) & 1) * 8192 + b * 1024 + sp] = vt + Mbuf[bt * 1024 + sp];
    }
}

// ---------- VO[bt][d] = b_out[d] + sum_s v[bt][s]*W_out[d][s] ----------
__global__ __launch_bounds__(256) void k_vo(const float* __restrict__ v,
                                            const float* __restrict__ Wout,
                                            const float* __restrict__ bout,
                                            float* __restrict__ VO) {
    int gw   = blockIdx.x * 4 + (threadIdx.x >> 6);  // 0..131071
    int bt   = gw >> 10;
    int d    = gw & 1023;
    int lane = threadIdx.x & 63;
    const float* vp = v + (long)bt * 1024 + lane * 16;
    const float* wp = Wout + (long)d * 1024 + lane * 16;
    float acc = 0.f;
#pragma unroll
    for (int i = 0; i < 4; ++i) {
        float4 a = *(const float4*)(vp + i * 4);
        float4 s = *(const float4*)(wp + i * 4);
        acc += a.x * s.x + a.y * s.y + a.z * s.z + a.w * s.w;
    }
#pragma unroll
    for (int off = 32; off; off >>= 1) acc += __shfl_xor(acc, off);
    if (lane == 0) VO[(long)bt * 1024 + d] = acc + bout[d];
}

// ---------- host launch ----------
extern "C" void kernel_launch(void* const* d_in, const int* in_sizes, int n_in,
                              void* d_out, int out_size, void* d_ws, size_t ws_size,
                              hipStream_t stream) {
    const float* x    = (const float*)d_in[0];
    const float* pos  = (const float*)d_in[1];
    const float* W_in = (const float*)d_in[2];
    const float* b_in = (const float*)d_in[3];
    const float* W_out= (const float*)d_in[4];
    const float* b_out= (const float*)d_in[5];
    const float* A    = (const float*)d_in[6];
    const float* Bm   = (const float*)d_in[7];
    const float* is0  = (const float*)d_in[8];
    float* out = (float*)d_out;

    // workspace layout (bytes)
    char* ws = (char*)d_ws;
    const size_t o_XPPB  = 0;                       // 64 MB  (XP, later aliased as PB)
    const size_t o_proj  = 67108864;                // 64 MB
    const size_t o_Win   = 134217728;               // 2 MB
    const size_t o_BmT   = 136314880;               // 2 MB
    const size_t o_Wout  = 138412032;               // 2 MB
    const size_t o_AT    = 140509184;               // 4 MB
    const size_t o_M     = 144703488;               // 512 KB
    const size_t o_v     = 145227776;               // 512 KB
    const size_t o_VO    = 145752064;               // 512 KB
    const size_t o_state = 146276352;               // 64 KB
    const size_t need    = 146341888;
    if (ws_size < need) return;  // workspace too small — fail loudly via wrong output

    __bf16* XP    = (__bf16*)(ws + o_XPPB);
    __bf16* PB    = (__bf16*)(ws + o_XPPB);   // alias: XP dead after GEMM1
    __bf16* proj  = (__bf16*)(ws + o_proj);
    __bf16* Win16 = (__bf16*)(ws + o_Win);
    __bf16* BmT   = (__bf16*)(ws + o_BmT);
    __bf16* Wout16= (__bf16*)(ws + o_Wout);
    float*  AT    = (float*)(ws + o_AT);
    float*  Mbuf  = (float*)(ws + o_M);
    float*  v     = (float*)(ws + o_v);
    float*  VO    = (float*)(ws + o_VO);
    float*  state = (float*)(ws + o_state);

    // prep
    k_cast<<<512, 256, 0, stream>>>(W_in, Win16, SS * DD);
    k_cast<<<512, 256, 0, stream>>>(W_out, Wout16, DD * SS);
    k_transpose_bf<<<dim3(32, 32), dim3(32, 32), 0, stream>>>(Bm, BmT);
    k_transpose_f32<<<dim3(32, 32), dim3(32, 32), 0, stream>>>(A, AT);
    k_xp<<<16384, 256, 0, stream>>>(x, pos, XP);
    k_init_state<<<32, 256, 0, stream>>>(is0, state);

    // GEMM1: proj = XP * W_in^T + b_in   (bf16 out)
    gemm_nt<0><<<dim3(256, 8), 256, 0, stream>>>(XP, Win16, (void*)proj, b_in, nullptr);
    // GEMM2: PB = proj * BmT^T (= proj @ Bm)  (bf16 out, overwrites XP)
    gemm_nt<1><<<dim3(256, 8), 256, 0, stream>>>(proj, BmT, (void*)PB, nullptr, nullptr);
    // column means
    k_mean<<<128, 128, 0, stream>>>(PB, Mbuf);
    // 16-step recurrence (tiny)
    for (int t = 0; t < 16; ++t)
        k_step<<<2048, 256, 0, stream>>>(AT, Mbuf, v, state, t);
    // VO = v * W_out^T + b_out
    k_vo<<<32768, 256, 0, stream>>>(v, W_out, b_out, VO);
    // GEMM3: out = PB * W_out^T + VO  (fp32 out)
    gemm_nt<2><<<dim3(256, 8), 256, 0, stream>>>(PB, Wout16, (void*)out, nullptr, VO);
}

// Round 2
// 579.588 us; speedup vs baseline: 1.2963x; 1.2963x over previous
//
#include <hip/hip_runtime.h>
#include <hip/hip_bf16.h>
#include <stdint.h>

// ---------- types ----------
typedef __bf16  bf16x8 __attribute__((ext_vector_type(8)));
typedef __bf16  bf16x4 __attribute__((ext_vector_type(4)));
typedef float   f32x4  __attribute__((ext_vector_type(4)));

// Problem constants
#define BSZ   8
#define TT    16
#define PP    256
#define DD    1024
#define SS    1024
#define MROWS (BSZ * TT * PP)        // 32768

// ---------- async global->LDS (16B per lane, wave-uniform LDS base) ----------
__device__ __forceinline__ void gload16(const void* g, void* l) {
    __builtin_amdgcn_global_load_lds(
        (const __attribute__((address_space(1))) void*)g,
        (__attribute__((address_space(3))) void*)l,
        16, 0, 0);
}

// ---------- fused: XP = bf16(x + pos), partial col-sums per 32-row slab ----------
// grid 1024 blocks: block handles 32 rows (1/8 of a (b,t) group of 256 rows)
__global__ __launch_bounds__(256) void k_xp_mean(const float* __restrict__ x,
                                                 const float* __restrict__ pos,
                                                 __bf16* __restrict__ xp,
                                                 float* __restrict__ part) {
    const int  blk = blockIdx.x;          // 0..1023
    const int  c0  = threadIdx.x * 4;     // 4 cols per thread
    const long r0  = (long)blk * 32;
    float s0 = 0.f, s1 = 0.f, s2 = 0.f, s3 = 0.f;
#pragma unroll 2
    for (int r = 0; r < 32; ++r) {
        long row = r0 + r;
        long xi  = row * 1024 + c0;
        long pi  = (row & 4095) * 1024 + c0;   // pos row = t*256+p = row mod 4096
        float4 a = *(const float4*)(x + xi);
        float4 p = *(const float4*)(pos + pi);
        float v0 = a.x + p.x, v1 = a.y + p.y, v2 = a.z + p.z, v3 = a.w + p.w;
        bf16x4 o; o[0] = (__bf16)v0; o[1] = (__bf16)v1; o[2] = (__bf16)v2; o[3] = (__bf16)v3;
        *(bf16x4*)(xp + xi) = o;
        s0 += v0; s1 += v1; s2 += v2; s3 += v3;
    }
    float4 s = {s0, s1, s2, s3};
    *(float4*)(part + (long)blk * 1024 + c0) = s;
}

// ---------- XPmean[g][c] = (1/256) * sum_{sub<8} part[g*8+sub][c] ----------
__global__ __launch_bounds__(256) void k_pmean(const float* __restrict__ part,
                                               float* __restrict__ xpm) {
    int idx = blockIdx.x * 256 + threadIdx.x;   // 0..131071
    int g = idx >> 10, c = idx & 1023;
    const float* p = part + (long)g * 8192 + c;
    float s = 0.f;
#pragma unroll
    for (int j = 0; j < 8; ++j) s += p[j * 1024];
    xpm[idx] = s * (1.0f / 256.0f);
}

// ---------- cast fp32 -> bf16 ----------
__global__ __launch_bounds__(256) void k_cast(const float* __restrict__ in,
                                              __bf16* __restrict__ out, int n) {
    int i = (blockIdx.x * blockDim.x + threadIdx.x) * 8;
    if (i >= n) return;
    float4 a = *(const float4*)(in + i);
    float4 b = *(const float4*)(in + i + 4);
    bf16x8 o;
    o[0] = (__bf16)a.x; o[1] = (__bf16)a.y; o[2] = (__bf16)a.z; o[3] = (__bf16)a.w;
    o[4] = (__bf16)b.x; o[5] = (__bf16)b.y; o[6] = (__bf16)b.z; o[7] = (__bf16)b.w;
    *(bf16x8*)(out + i) = o;
}

// ---------- transpose 1024x1024 ----------
__global__ void k_transpose_bf(const float* __restrict__ in, __bf16* __restrict__ out) {
    __shared__ float tile[32][33];
    int x = blockIdx.x * 32 + threadIdx.x;
    int y = blockIdx.y * 32 + threadIdx.y;
    tile[threadIdx.y][threadIdx.x] = in[(long)y * 1024 + x];
    __syncthreads();
    int ox = blockIdx.y * 32 + threadIdx.x;
    int oy = blockIdx.x * 32 + threadIdx.y;
    out[(long)oy * 1024 + ox] = (__bf16)tile[threadIdx.x][threadIdx.y];
}

__global__ void k_transpose_f32(const float* __restrict__ in, float* __restrict__ out) {
    __shared__ float tile[32][33];
    int x = blockIdx.x * 32 + threadIdx.x;
    int y = blockIdx.y * 32 + threadIdx.y;
    tile[threadIdx.y][threadIdx.x] = in[(long)y * 1024 + x];
    __syncthreads();
    int ox = blockIdx.y * 32 + threadIdx.x;
    int oy = blockIdx.x * 32 + threadIdx.y;
    out[(long)oy * 1024 + ox] = tile[threadIdx.x][threadIdx.y];
}

// ---------- NT GEMM: C[m,n] = sum_k A[m,k]*B[n,k], K=1024 fixed ----------
// 128x128 tile, BK=64, 256 threads (4 waves, 2x2), mfma_f32_16x16x32_bf16.
// EPI: 1 = bf16 out; 2 = f32 out + VO[(m>>8)*1024+n]
template <int EPI>
__global__ __launch_bounds__(256) void gemm_nt(const __bf16* __restrict__ A,
                                               const __bf16* __restrict__ B,
                                               void* __restrict__ Cout,
                                               const float* __restrict__ VO) {
    constexpr int K = 1024;
    const int tid  = threadIdx.x;
    const int lane = tid & 63;
    const int w    = tid >> 6;          // wave 0..3
    const int wr   = w >> 1, wc = w & 1;
    const long bm  = (long)blockIdx.x * 128;
    const long bn  = (long)blockIdx.y * 128;

    __shared__ __bf16 As[128 * 64];
    __shared__ __bf16 Bs[128 * 64];

    f32x4 acc[4][4];
#pragma unroll
    for (int i = 0; i < 4; ++i)
#pragma unroll
        for (int j = 0; j < 4; ++j) acc[i][j] = (f32x4){0.f, 0.f, 0.f, 0.f};

    const int sr = (w << 3) + (lane >> 3);    // + j*32
    const int sc = (lane & 7) << 3;
    const __bf16* Ap = A + (bm + sr) * K + sc;
    const __bf16* Bp = B + (bn + sr) * K + sc;

    for (int kt = 0; kt < K; kt += 64) {
        if (kt) __syncthreads();
#pragma unroll
        for (int j = 0; j < 4; ++j) {
            gload16(Ap + (long)j * 32 * K + kt, &As[j * 2048 + w * 512]);
            gload16(Bp + (long)j * 32 * K + kt, &Bs[j * 2048 + w * 512]);
        }
        __syncthreads();

#pragma unroll
        for (int kk = 0; kk < 2; ++kk) {
            const int ko = kk * 32 + ((lane >> 4) << 3);
            bf16x8 af[4], bfr[4];
#pragma unroll
            for (int i = 0; i < 4; ++i) {
                int ar = wr * 64 + i * 16 + (lane & 15);
                af[i]  = *(const bf16x8*)&As[ar * 64 + ko];
                int br = wc * 64 + i * 16 + (lane & 15);
                bfr[i] = *(const bf16x8*)&Bs[br * 64 + ko];
            }
#pragma unroll
            for (int mi = 0; mi < 4; ++mi)
#pragma unroll
                for (int ni = 0; ni < 4; ++ni)
                    acc[mi][ni] = __builtin_amdgcn_mfma_f32_16x16x32_bf16(
                        af[mi], bfr[ni], acc[mi][ni], 0, 0, 0);
        }
    }

    // epilogue: C/D layout col=lane&15, row=(lane>>4)*4+j  [m89-verified]
    const int r0 = (lane >> 4) << 2;
    const int c0 = lane & 15;
#pragma unroll
    for (int mi = 0; mi < 4; ++mi) {
#pragma unroll
        for (int ni = 0; ni < 4; ++ni) {
#pragma unroll
            for (int j = 0; j < 4; ++j) {
                long gm = bm + wr * 64 + mi * 16 + r0 + j;
                long gn = bn + wc * 64 + ni * 16 + c0;
                float val = acc[mi][ni][j];
                if constexpr (EPI == 1) {
                    ((__bf16*)Cout)[gm * 1024 + gn] = (__bf16)val;
                } else {
                    ((float*)Cout)[gm * 1024 + gn] = val + VO[(gm >> 8) * 1024 + gn];
                }
            }
        }
    }
}

// ---------- small fp32 NT GEMM: C[128,1024] = A[128,1024] @ B[1024,1024]^T ----------
// grid (16,8): tile 8m x 128n, 256 threads, K split in 2 halves per thread pair
template <int BIAS>
__global__ __launch_bounds__(256) void small_nt(const float* __restrict__ A,
                                                const float* __restrict__ B,
                                                float* __restrict__ C,
                                                const float* __restrict__ bias1,
                                                const float* __restrict__ bias2) {
    __shared__ float Asm[8][1024];
    __shared__ float Red[128][8];
    const int m0  = blockIdx.x * 8;
    const int n0  = blockIdx.y * 128;
    const int tid = threadIdx.x;
#pragma unroll
    for (int j = 0; j < 8; ++j) {
        int fi = j * 1024 + tid * 4;
        *(float4*)(&Asm[0][0] + fi) = *(const float4*)(A + (long)m0 * 1024 + fi);
    }
    __syncthreads();
    const int n  = n0 + (tid & 127);
    const int kh = tid >> 7;
    float p[8];
#pragma unroll
    for (int m = 0; m < 8; ++m) p[m] = 0.f;
    const float* Bp = B + (long)n * 1024 + kh * 512;
    for (int k = 0; k < 512; k += 4) {
        float4 bv = *(const float4*)(Bp + k);
        int kk = kh * 512 + k;
#pragma unroll
        for (int m = 0; m < 8; ++m)
            p[m] += Asm[m][kk] * bv.x + Asm[m][kk + 1] * bv.y +
                    Asm[m][kk + 2] * bv.z + Asm[m][kk + 3] * bv.w;
    }
    if (kh) {
#pragma unroll
        for (int m = 0; m < 8; ++m) Red[tid & 127][m] = p[m];
    }
    __syncthreads();
    if (!kh) {
#pragma unroll
        for (int m = 0; m < 8; ++m) {
            float vv = p[m] + Red[tid][m];
            if (BIAS >= 1) vv += bias1[n];
            if (BIAS >= 2) vv += bias2[n];
            C[(long)(m0 + m) * 1024 + n] = vv;
        }
    }
}

// ---------- bb[d] = sum_s b_in[s] * BWT[d][s] ----------
__global__ __launch_bounds__(256) void k_bb(const __bf16* __restrict__ BWT,
                                            const float* __restrict__ b_in,
                                            float* __restrict__ bb) {
    int d    = blockIdx.x * 4 + (threadIdx.x >> 6);
    int lane = threadIdx.x & 63;
    const __bf16* row = BWT + (long)d * 1024 + lane * 16;
    float acc = 0.f;
#pragma unroll
    for (int i = 0; i < 2; ++i) {
        bf16x8 v = *(const bf16x8*)(row + i * 8);
        const float* bi = b_in + lane * 16 + i * 8;
#pragma unroll
        for (int j = 0; j < 8; ++j) acc += (float)v[j] * bi[j];
    }
#pragma unroll
    for (int off = 32; off; off >>= 1) acc += __shfl_xor(acc, off);
    if (!lane) bb[d] = acc;
}

// ---------- state init ----------
__global__ __launch_bounds__(256) void k_init_state(const float* __restrict__ init,
                                                    float* __restrict__ state) {
    int idx = blockIdx.x * 256 + threadIdx.x;   // 0..8191
    state[idx] = init[idx & 1023];
}

// ---------- scan step t ----------
__global__ __launch_bounds__(256) void k_step(const float* __restrict__ AT,
                                              const float* __restrict__ Mbuf,
                                              float* __restrict__ v,
                                              float* __restrict__ state,  // [2][8192]
                                              int t) {
    int gw   = blockIdx.x * 4 + (threadIdx.x >> 6);  // 0..8191
    int b    = gw >> 10;
    int sp   = gw & 1023;
    int lane = threadIdx.x & 63;
    const float* at = AT + (long)sp * 1024 + lane * 16;
    const float* st = state + (t & 1) * 8192 + b * 1024 + lane * 16;
    float acc = 0.f;
#pragma unroll
    for (int i = 0; i < 4; ++i) {
        float4 a = *(const float4*)(at + i * 4);
        float4 s = *(const float4*)(st + i * 4);
        acc += a.x * s.x + a.y * s.y + a.z * s.z + a.w * s.w;
    }
#pragma unroll
    for (int off = 32; off; off >>= 1) acc += __shfl_xor(acc, off);
    if (lane == 0) {
        float vt = acc;
        long bt = (long)b * 16 + t;
        v[bt * 1024 + sp] = vt;
        state[((t + 1) & 1) * 8192 + b * 1024 + sp] = vt + Mbuf[bt * 1024 + sp];
    }
}

// ---------- host launch ----------
extern "C" void kernel_launch(void* const* d_in, const int* in_sizes, int n_in,
                              void* d_out, int out_size, void* d_ws, size_t ws_size,
                              hipStream_t stream) {
    const float* x    = (const float*)d_in[0];
    const float* pos  = (const float*)d_in[1];
    const float* W_in = (const float*)d_in[2];
    const float* b_in = (const float*)d_in[3];
    const float* W_out= (const float*)d_in[4];
    const float* b_out= (const float*)d_in[5];
    const float* A    = (const float*)d_in[6];
    const float* Bm   = (const float*)d_in[7];
    const float* is0  = (const float*)d_in[8];
    float* out = (float*)d_out;

    // workspace layout (bytes)
    char* ws = (char*)d_ws;
    const size_t o_XP     = 0;             // 64 MB
    const size_t o_Part   = 67108864;      // 4 MB
    const size_t o_XPm    = 71303168;      // 512 KB
    const size_t o_projM  = 71827456;      // 512 KB
    const size_t o_Mbuf   = 72351744;      // 512 KB
    const size_t o_v      = 72876032;      // 512 KB
    const size_t o_VO     = 73400320;      // 512 KB
    const size_t o_state  = 73924608;      // 64 KB
    const size_t o_bb     = 73990144;      // 4 KB
    const size_t o_AT     = 73994240;      // 4 MB
    const size_t o_BmT    = 78188544;      // 4 MB
    const size_t o_Wout16 = 82382848;      // 2 MB
    const size_t o_Bm16   = 84480000;      // 2 MB
    const size_t o_WinT16 = 86577152;      // 2 MB
    const size_t o_BWT    = 88674304;      // 2 MB
    const size_t o_G      = 90771456;      // 2 MB
    const size_t need     = 92868608;
    if (ws_size < need) return;

    __bf16* XP     = (__bf16*)(ws + o_XP);
    float*  Part   = (float*)(ws + o_Part);
    float*  XPm    = (float*)(ws + o_XPm);
    float*  projM  = (float*)(ws + o_projM);
    float*  Mbuf   = (float*)(ws + o_Mbuf);
    float*  v      = (float*)(ws + o_v);
    float*  VO     = (float*)(ws + o_VO);
    float*  state  = (float*)(ws + o_state);
    float*  bb     = (float*)(ws + o_bb);
    float*  AT     = (float*)(ws + o_AT);
    float*  BmT    = (float*)(ws + o_BmT);
    __bf16* Wout16 = (__bf16*)(ws + o_Wout16);
    __bf16* Bm16   = (__bf16*)(ws + o_Bm16);
    __bf16* WinT16 = (__bf16*)(ws + o_WinT16);
    __bf16* BWT    = (__bf16*)(ws + o_BWT);
    __bf16* G      = (__bf16*)(ws + o_G);

    // prep (all tiny)
    k_cast<<<512, 256, 0, stream>>>(W_out, Wout16, SS * DD);
    k_cast<<<512, 256, 0, stream>>>(Bm, Bm16, SS * SS);
    k_transpose_bf<<<dim3(32, 32), dim3(32, 32), 0, stream>>>(W_in, WinT16);
    k_transpose_f32<<<dim3(32, 32), dim3(32, 32), 0, stream>>>(A, AT);
    k_transpose_f32<<<dim3(32, 32), dim3(32, 32), 0, stream>>>(Bm, BmT);
    k_init_state<<<32, 256, 0, stream>>>(is0, state);

    // XP = bf16(x+pos) with fused partial col-sums; then group means
    k_xp_mean<<<1024, 256, 0, stream>>>(x, pos, XP, Part);
    k_pmean<<<512, 256, 0, stream>>>(Part, XPm);

    // weight folding: BWT[d,s] = sum_s' Wout[d,s']*Bm[s,s']  (= (Bm @ Wout^T)^T)
    //                 G[n,k]   = sum_s BWT[n,s]*W_in[s,k]    (= (W_in^T Bm Wout^T)^T)
    gemm_nt<1><<<dim3(8, 8), 256, 0, stream>>>(Wout16, Bm16, (void*)BWT, nullptr);
    gemm_nt<1><<<dim3(8, 8), 256, 0, stream>>>(BWT, WinT16, (void*)G, nullptr);
    k_bb<<<256, 256, 0, stream>>>(BWT, b_in, bb);

    // scan input: projM = XPm @ W_in^T + b_in ; Mbuf = projM @ Bm
    small_nt<1><<<dim3(16, 8), 256, 0, stream>>>(XPm, W_in, projM, b_in, nullptr);
    small_nt<0><<<dim3(16, 8), 256, 0, stream>>>(projM, BmT, Mbuf, nullptr, nullptr);

    // 16-step recurrence (tiny)
    for (int t = 0; t < 16; ++t)
        k_step<<<2048, 256, 0, stream>>>(AT, Mbuf, v, state, t);

    // VO[bt,d] = v[bt]@W_out^T + b_out + bb
    small_nt<2><<<dim3(16, 8), 256, 0, stream>>>(v, W_out, VO, b_out, bb);

    // out = XP @ G^T(row-major G[n,k]) + VO   — the single big GEMM
    gemm_nt<2><<<dim3(256, 8), 256, 0, stream>>>(XP, G, (void*)out, VO);
}

// Round 5
// 575.490 us; speedup vs baseline: 1.3055x; 1.0071x over previous
//
#include <hip/hip_runtime.h>
#include <hip/hip_bf16.h>
#include <stdint.h>

// ---------- types ----------
typedef __bf16  bf16x8 __attribute__((ext_vector_type(8)));
typedef __bf16  bf16x4 __attribute__((ext_vector_type(4)));
typedef float   f32x4  __attribute__((ext_vector_type(4)));

// Problem constants
#define BSZ   8
#define TT    16
#define PP    256
#define DD    1024
#define SS    1024

// ---------- async global->LDS (16B per lane, wave-uniform LDS base) ----------
__device__ __forceinline__ void gload16(const void* g, void* l) {
    __builtin_amdgcn_global_load_lds(
        (const __attribute__((address_space(1))) void*)g,
        (__attribute__((address_space(3))) void*)l,
        16, 0, 0);
}

// ---------- fused prep: casts + transposes ----------
// bx [0,512): cast Wout->bf16 ; [512,1024): cast Bm->bf16
// bx [1024,2048): transpose W_in -> WinT16 (bf16)
// bx [2048,3072): transpose A -> AT (f32)
__global__ __launch_bounds__(256) void k_prep(const float* __restrict__ Wout, __bf16* __restrict__ Wout16,
                                              const float* __restrict__ Bm,   __bf16* __restrict__ Bm16,
                                              const float* __restrict__ Win,  __bf16* __restrict__ WinT16,
                                              const float* __restrict__ A,    float* __restrict__ AT) {
    const int bx = blockIdx.x;
    if (bx < 1024) {  // two cast jobs, 512 blocks each
        const float* src = (bx < 512) ? Wout : Bm;
        __bf16* dst = (bx < 512) ? Wout16 : Bm16;
        int i = ((bx & 511) * 256 + threadIdx.x) * 8;
        float4 a = *(const float4*)(src + i);
        float4 b = *(const float4*)(src + i + 4);
        bf16x8 o;
        o[0] = (__bf16)a.x; o[1] = (__bf16)a.y; o[2] = (__bf16)a.z; o[3] = (__bf16)a.w;
        o[4] = (__bf16)b.x; o[5] = (__bf16)b.y; o[6] = (__bf16)b.z; o[7] = (__bf16)b.w;
        *(bf16x8*)(dst + i) = o;
    } else if (bx < 2048) {  // transpose W_in (1024x1024) -> bf16
        __shared__ float tile[32][33];
        int tb = bx - 1024;
        int tx = tb & 31, ty = tb >> 5;
        int lx = threadIdx.x & 31, ly = threadIdx.x >> 5;   // 32x8
#pragma unroll
        for (int r = 0; r < 32; r += 8)
            tile[ly + r][lx] = Win[(long)(ty * 32 + ly + r) * 1024 + tx * 32 + lx];
        __syncthreads();
#pragma unroll
        for (int r = 0; r < 32; r += 8)
            WinT16[(long)(tx * 32 + ly + r) * 1024 + ty * 32 + lx] = (__bf16)tile[lx][ly + r];
    } else {  // transpose A (1024x1024) -> f32
        __shared__ float tile[32][33];
        int tb = bx - 2048;
        int tx = tb & 31, ty = tb >> 5;
        int lx = threadIdx.x & 31, ly = threadIdx.x >> 5;
#pragma unroll
        for (int r = 0; r < 32; r += 8)
            tile[ly + r][lx] = A[(long)(ty * 32 + ly + r) * 1024 + tx * 32 + lx];
        __syncthreads();
#pragma unroll
        for (int r = 0; r < 32; r += 8)
            AT[(long)(tx * 32 + ly + r) * 1024 + ty * 32 + lx] = tile[lx][ly + r];
    }
}

// ---------- fused: XP = bf16(x + pos), partial col-sums per 32-row slab ----------
__global__ __launch_bounds__(256) void k_xp_mean(const float* __restrict__ x,
                                                 const float* __restrict__ pos,
                                                 __bf16* __restrict__ xp,
                                                 float* __restrict__ part) {
    const int  blk = blockIdx.x;          // 0..1023
    const int  c0  = threadIdx.x * 4;     // 4 cols per thread
    const long r0  = (long)blk * 32;
    float s0 = 0.f, s1 = 0.f, s2 = 0.f, s3 = 0.f;
#pragma unroll 2
    for (int r = 0; r < 32; ++r) {
        long row = r0 + r;
        long xi  = row * 1024 + c0;
        long pi  = (row & 4095) * 1024 + c0;   // pos row = t*256+p = row mod 4096
        float4 a = *(const float4*)(x + xi);
        float4 p = *(const float4*)(pos + pi);
        float v0 = a.x + p.x, v1 = a.y + p.y, v2 = a.z + p.z, v3 = a.w + p.w;
        bf16x4 o; o[0] = (__bf16)v0; o[1] = (__bf16)v1; o[2] = (__bf16)v2; o[3] = (__bf16)v3;
        *(bf16x4*)(xp + xi) = o;
        s0 += v0; s1 += v1; s2 += v2; s3 += v3;
    }
    float4 s = {s0, s1, s2, s3};
    *(float4*)(part + (long)blk * 1024 + c0) = s;
}

// ---------- XPmean[g][c] = (1/256) * sum_{sub<8} part[g*8+sub][c] ----------
__global__ __launch_bounds__(256) void k_pmean(const float* __restrict__ part,
                                               float* __restrict__ xpm) {
    int idx = blockIdx.x * 256 + threadIdx.x;   // 0..131071
    int g = idx >> 10, c = idx & 1023;
    const float* p = part + (long)g * 8192 + c;
    float s = 0.f;
#pragma unroll
    for (int j = 0; j < 8; ++j) s += p[j * 1024];
    xpm[idx] = s * (1.0f / 256.0f);
}

// ---------- NT GEMM: C[m,n] = sum_k A[m,k]*B[n,k], K=1024, N=1024 (8 n-blocks) ----------
// 128x128 tile, BK=64, 256 threads (4 waves, 2x2), mfma_f32_16x16x32_bf16.
// 1D grid (M/128)*8 with bijective XCD swizzle, n-fast within each XCD chunk.
// EPI: 1 = bf16 out; 2 = f32 out + VO[(m>>8)*1024+n]
template <int EPI>
__global__ __launch_bounds__(256) void gemm_nt(const __bf16* __restrict__ A,
                                               const __bf16* __restrict__ B,
                                               void* __restrict__ Cout,
                                               const float* __restrict__ VO) {
    constexpr int K = 1024;
    const int tid  = threadIdx.x;
    const int lane = tid & 63;
    const int w    = tid >> 6;          // wave 0..3
    const int wr   = w >> 1, wc = w & 1;
    // XCD-aware swizzle (nwg % 8 == 0): same-XCD blocks get consecutive work,
    // n-fast so the 2MB B panel stays L2-resident per XCD.
    const int cpx = gridDim.x >> 3;
    const int swz = (blockIdx.x & 7) * cpx + (blockIdx.x >> 3);
    const long bm = (long)(swz >> 3) * 128;
    const long bn = (long)(swz & 7) * 128;

    __shared__ __bf16 As[128 * 64];
    __shared__ __bf16 Bs[128 * 64];

    f32x4 acc[4][4];
#pragma unroll
    for (int i = 0; i < 4; ++i)
#pragma unroll
        for (int j = 0; j < 4; ++j) acc[i][j] = (f32x4){0.f, 0.f, 0.f, 0.f};

    const int sr = (w << 3) + (lane >> 3);    // + j*32
    const int sc = (lane & 7) << 3;
    const __bf16* Ap = A + (bm + sr) * K + sc;
    const __bf16* Bp = B + (bn + sr) * K + sc;

    for (int kt = 0; kt < K; kt += 64) {
        if (kt) __syncthreads();
#pragma unroll
        for (int j = 0; j < 4; ++j) {
            gload16(Ap + (long)j * 32 * K + kt, &As[j * 2048 + w * 512]);
            gload16(Bp + (long)j * 32 * K + kt, &Bs[j * 2048 + w * 512]);
        }
        __syncthreads();

#pragma unroll
        for (int kk = 0; kk < 2; ++kk) {
            const int ko = kk * 32 + ((lane >> 4) << 3);
            bf16x8 af[4], bfr[4];
#pragma unroll
            for (int i = 0; i < 4; ++i) {
                int ar = wr * 64 + i * 16 + (lane & 15);
                af[i]  = *(const bf16x8*)&As[ar * 64 + ko];
                int br = wc * 64 + i * 16 + (lane & 15);
                bfr[i] = *(const bf16x8*)&Bs[br * 64 + ko];
            }
#pragma unroll
            for (int mi = 0; mi < 4; ++mi)
#pragma unroll
                for (int ni = 0; ni < 4; ++ni)
                    acc[mi][ni] = __builtin_amdgcn_mfma_f32_16x16x32_bf16(
                        af[mi], bfr[ni], acc[mi][ni], 0, 0, 0);
        }
    }

    // epilogue: C/D layout col=lane&15, row=(lane>>4)*4+j  [m89-verified]
    const int r0 = (lane >> 4) << 2;
    const int c0 = lane & 15;
#pragma unroll
    for (int mi = 0; mi < 4; ++mi) {
#pragma unroll
        for (int ni = 0; ni < 4; ++ni) {
#pragma unroll
            for (int j = 0; j < 4; ++j) {
                long gm = bm + wr * 64 + mi * 16 + r0 + j;
                long gn = bn + wc * 64 + ni * 16 + c0;
                float val = acc[mi][ni][j];
                if constexpr (EPI == 1) {
                    ((__bf16*)Cout)[gm * 1024 + gn] = (__bf16)val;
                } else {
                    ((float*)Cout)[gm * 1024 + gn] = val + VO[(gm >> 8) * 1024 + gn];
                }
            }
        }
    }
}

// ---------- small fp32 NT GEMM: C[128,1024] = A[128,1024] @ B^T, B row-major [n][k] ----------
template <int BIAS>
__global__ __launch_bounds__(256) void small_nt(const float* __restrict__ A,
                                                const float* __restrict__ B,
                                                float* __restrict__ C,
                                                const float* __restrict__ bias1,
                                                const float* __restrict__ bias2) {
    __shared__ float Asm[8][1024];
    __shared__ float Red[128][8];
    const int m0  = blockIdx.x * 8;
    const int n0  = blockIdx.y * 128;
    const int tid = threadIdx.x;
#pragma unroll
    for (int j = 0; j < 8; ++j) {
        int fi = j * 1024 + tid * 4;
        *(float4*)(&Asm[0][0] + fi) = *(const float4*)(A + (long)m0 * 1024 + fi);
    }
    __syncthreads();
    const int n  = n0 + (tid & 127);
    const int kh = tid >> 7;
    float p[8];
#pragma unroll
    for (int m = 0; m < 8; ++m) p[m] = 0.f;
    const float* Bp = B + (long)n * 1024 + kh * 512;
    for (int k = 0; k < 512; k += 4) {
        float4 bv = *(const float4*)(Bp + k);
        int kk = kh * 512 + k;
#pragma unroll
        for (int m = 0; m < 8; ++m)
            p[m] += Asm[m][kk] * bv.x + Asm[m][kk + 1] * bv.y +
                    Asm[m][kk + 2] * bv.z + Asm[m][kk + 3] * bv.w;
    }
    if (kh) {
#pragma unroll
        for (int m = 0; m < 8; ++m) Red[tid & 127][m] = p[m];
    }
    __syncthreads();
    if (!kh) {
#pragma unroll
        for (int m = 0; m < 8; ++m) {
            float vv = p[m] + Red[tid][m];
            if (BIAS >= 1) vv += bias1[n];
            if (BIAS >= 2) vv += bias2[n];
            C[(long)(m0 + m) * 1024 + n] = vv;
        }
    }
}

// ---------- small fp32 NN GEMM: C[128,1024] = A[128,1024] @ B, B row-major [k][n] ----------
__global__ __launch_bounds__(256) void small_nn(const float* __restrict__ A,
                                                const float* __restrict__ B,
                                                float* __restrict__ C) {
    __shared__ float Asm[8][1024];
    __shared__ float Red[128][8];
    const int m0  = blockIdx.x * 8;
    const int n0  = blockIdx.y * 128;
    const int tid = threadIdx.x;
#pragma unroll
    for (int j = 0; j < 8; ++j) {
        int fi = j * 1024 + tid * 4;
        *(float4*)(&Asm[0][0] + fi) = *(const float4*)(A + (long)m0 * 1024 + fi);
    }
    __syncthreads();
    const int n  = n0 + (tid & 127);
    const int kh = tid >> 7;
    float p[8];
#pragma unroll
    for (int m = 0; m < 8; ++m) p[m] = 0.f;
    const float* Bp = B + n + (long)kh * 512 * 1024;
    for (int k = 0; k < 512; ++k) {
        float bv = Bp[(long)k * 1024];
        int kk = kh * 512 + k;
#pragma unroll
        for (int m = 0; m < 8; ++m) p[m] += Asm[m][kk] * bv;
    }
    if (kh) {
#pragma unroll
        for (int m = 0; m < 8; ++m) Red[tid & 127][m] = p[m];
    }
    __syncthreads();
    if (!kh) {
#pragma unroll
        for (int m = 0; m < 8; ++m)
            C[(long)(m0 + m) * 1024 + n] = p[m] + Red[tid][m];
    }
}

// ---------- bb[d] = sum_s b_in[s] * BWT[d][s] ----------
__global__ __launch_bounds__(256) void k_bb(const __bf16* __restrict__ BWT,
                                            const float* __restrict__ b_in,
                                            float* __restrict__ bb) {
    int d    = blockIdx.x * 4 + (threadIdx.x >> 6);
    int lane = threadIdx.x & 63;
    const __bf16* row = BWT + (long)d * 1024 + lane * 16;
    float acc = 0.f;
#pragma unroll
    for (int i = 0; i < 2; ++i) {
        bf16x8 v = *(const bf16x8*)(row + i * 8);
        const float* bi = b_in + lane * 16 + i * 8;
#pragma unroll
        for (int j = 0; j < 8; ++j) acc += (float)v[j] * bi[j];
    }
#pragma unroll
    for (int off = 32; off; off >>= 1) acc += __shfl_xor(acc, off);
    if (!lane) bb[d] = acc;
}

// ---------- state init: state[b][s] = initial_state[s] ----------
__global__ __launch_bounds__(256) void k_init_state(const float* __restrict__ init,
                                                    float* __restrict__ state) {
    int idx = blockIdx.x * 256 + threadIdx.x;   // 0..8191
    state[idx] = init[idx & 1023];
}

// ---------- scan step t (proven round-2 version) ----------
__global__ __launch_bounds__(256) void k_step(const float* __restrict__ AT,
                                              const float* __restrict__ Mbuf,
                                              float* __restrict__ v,
                                              float* __restrict__ state,  // [2][8192]
                                              int t) {
    int gw   = blockIdx.x * 4 + (threadIdx.x >> 6);  // 0..8191
    int b    = gw >> 10;
    int sp   = gw & 1023;
    int lane = threadIdx.x & 63;
    const float* at = AT + (long)sp * 1024 + lane * 16;
    const float* st = state + (t & 1) * 8192 + b * 1024 + lane * 16;
    float acc = 0.f;
#pragma unroll
    for (int i = 0; i < 4; ++i) {
        float4 a = *(const float4*)(at + i * 4);
        float4 s = *(const float4*)(st + i * 4);
        acc += a.x * s.x + a.y * s.y + a.z * s.z + a.w * s.w;
    }
#pragma unroll
    for (int off = 32; off; off >>= 1) acc += __shfl_xor(acc, off);
    if (lane == 0) {
        float vt = acc;
        long bt = (long)b * 16 + t;
        v[bt * 1024 + sp] = vt;
        state[((t + 1) & 1) * 8192 + b * 1024 + sp] = vt + Mbuf[bt * 1024 + sp];
    }
}

// ---------- host launch ----------
extern "C" void kernel_launch(void* const* d_in, const int* in_sizes, int n_in,
                              void* d_out, int out_size, void* d_ws, size_t ws_size,
                              hipStream_t stream) {
    const float* x    = (const float*)d_in[0];
    const float* pos  = (const float*)d_in[1];
    const float* W_in = (const float*)d_in[2];
    const float* b_in = (const float*)d_in[3];
    const float* W_out= (const float*)d_in[4];
    const float* b_out= (const float*)d_in[5];
    const float* A    = (const float*)d_in[6];
    const float* Bm   = (const float*)d_in[7];
    const float* is0  = (const float*)d_in[8];
    float* out = (float*)d_out;

    // workspace layout (bytes)
    char* ws = (char*)d_ws;
    const size_t o_XP     = 0;             // 64 MB
    const size_t o_Part   = 67108864;      // 4 MB
    const size_t o_XPm    = 71303168;      // 512 KB
    const size_t o_projM  = 71827456;      // 512 KB
    const size_t o_Mbuf   = 72351744;      // 512 KB
    const size_t o_v      = 72876032;      // 512 KB
    const size_t o_VO     = 73400320;      // 512 KB
    const size_t o_bb     = 73924608;      // 64 KB (4 KB used)
    const size_t o_state  = 73990144;      // 64 KB
    const size_t o_AT     = 74055680;      // 4 MB
    const size_t o_Wout16 = 78249984;      // 2 MB
    const size_t o_Bm16   = 80347136;      // 2 MB
    const size_t o_WinT16 = 82444288;      // 2 MB
    const size_t o_BWT    = 84541440;      // 2 MB
    const size_t o_G      = 86638592;      // 2 MB
    const size_t need     = 88735744;
    if (ws_size < need) return;

    __bf16* XP     = (__bf16*)(ws + o_XP);
    float*  Part   = (float*)(ws + o_Part);
    float*  XPm    = (float*)(ws + o_XPm);
    float*  projM  = (float*)(ws + o_projM);
    float*  Mbuf   = (float*)(ws + o_Mbuf);
    float*  v      = (float*)(ws + o_v);
    float*  VO     = (float*)(ws + o_VO);
    float*  bb     = (float*)(ws + o_bb);
    float*  state  = (float*)(ws + o_state);
    float*  AT     = (float*)(ws + o_AT);
    __bf16* Wout16 = (__bf16*)(ws + o_Wout16);
    __bf16* Bm16   = (__bf16*)(ws + o_Bm16);
    __bf16* WinT16 = (__bf16*)(ws + o_WinT16);
    __bf16* BWT    = (__bf16*)(ws + o_BWT);
    __bf16* G      = (__bf16*)(ws + o_G);

    // 1. fused prep: casts + transposes (W_in -> bf16 T, A -> f32 T)
    k_prep<<<3072, 256, 0, stream>>>(W_out, Wout16, Bm, Bm16, W_in, WinT16, A, AT);
    // 2-3. XP = bf16(x+pos) + fused partial col-sums; then group means
    k_xp_mean<<<1024, 256, 0, stream>>>(x, pos, XP, Part);
    k_pmean<<<512, 256, 0, stream>>>(Part, XPm);
    // 4-5. weight folding: BWT[d,s'] = sum_s Wout[d,s]*Bm[s',s]; G[d,k] = sum_s' BWT[d,s']*W_in[s',k]
    gemm_nt<1><<<64, 256, 0, stream>>>(Wout16, Bm16, (void*)BWT, nullptr);
    gemm_nt<1><<<64, 256, 0, stream>>>(BWT, WinT16, (void*)G, nullptr);
    // 6. bb[d] = b_in @ BWT^T
    k_bb<<<256, 256, 0, stream>>>(BWT, b_in, bb);
    // 7-8. scan input: projM = XPm @ W_in^T + b_in ; Mbuf = projM @ Bm
    small_nt<1><<<dim3(16, 8), 256, 0, stream>>>(XPm, W_in, projM, b_in, nullptr);
    small_nn<<<dim3(16, 8), 256, 0, stream>>>(projM, Bm, Mbuf);
    // 9. init + 16-step recurrence (proven round-2 path)
    k_init_state<<<32, 256, 0, stream>>>(is0, state);
    for (int t = 0; t < 16; ++t)
        k_step<<<2048, 256, 0, stream>>>(AT, Mbuf, v, state, t);
    // 10. VO[bt,d] = v[bt] @ W_out^T + b_out + bb
    small_nt<2><<<dim3(16, 8), 256, 0, stream>>>(v, W_out, VO, b_out, bb);
    // 11. out = XP @ G^T + VO  — the single big GEMM
    gemm_nt<2><<<2048, 256, 0, stream>>>(XP, G, (void*)out, VO);
}